// Round 14
// baseline (264.606 us; speedup 1.0000x reference)
//
#include <hip/hip_runtime.h>
#include <hip/hip_cooperative_groups.h>
#include <hip/hip_fp8.h>
#include <stdint.h>

#define NPAIR 4096
#define N2    8192      // 2N rows
#define DIM   256
#define NTILE 8256      // 128*129/2 upper-triangle 64x64 tiles
#define CGRID 512       // cooperative grid blocks (2 blocks/CU -> always fits)
#define CWAVE (CGRID*4) // 2048 persistent waves
// inputs pre-scaled by sqrt(log2(e)/T): acc == log2(e)/T * sim
#define SCALE_IN 1.6986436f

namespace cg = cooperative_groups;

typedef long  f8frag;   // 8 fp8 elems = 2 VGPR (A/B operand of 16x16x32 fp8)
typedef float f32x4 __attribute__((ext_vector_type(4)));

static __device__ __forceinline__ uint8_t f2fp8(float f) {
    __hip_fp8_e4m3 v(f);                 // OCP e4m3fn, RNE saturating
    return *reinterpret_cast<uint8_t*>(&v);
}

// reps is stored FRAGMENT-TILED fp8: byte index of (row i, dim d) =
//   ((i>>4)*8 + (d>>5))*512 + ((d>>3)&3)*128 + (i&15)*8 + (d&7)
// an MFMA fragment (16 rows x 32 k; lane l -> row l&15, k-slot l>>4) is the
// contiguous 512B block at tile(i>>4, d>>5): lane l reads 8B at base + l*8.

// ---------------- shared phase bodies ----------------
static __device__ __forceinline__ void do_normalize(
    int i, int l, const float* __restrict__ emb_i,
    const float* __restrict__ emb_j, uint8_t* __restrict__ reps,
    float* __restrict__ pdot, float* __restrict__ rowsum) {
    float4 a = ((const float4*)(emb_i + (size_t)i * DIM))[l];
    float4 b = ((const float4*)(emb_j + (size_t)i * DIM))[l];
    float si = a.x*a.x + a.y*a.y + a.z*a.z + a.w*a.w;
    float sj = b.x*b.x + b.y*b.y + b.z*b.z + b.w*b.w;
    float dp = a.x*b.x + a.y*b.y + a.z*b.z + a.w*b.w;
    #pragma unroll
    for (int off = 32; off; off >>= 1) {
        si += __shfl_xor(si, off);
        sj += __shfl_xor(sj, off);
        dp += __shfl_xor(dp, off);
    }
    float ri = 1.0f / fmaxf(sqrtf(si), 1e-12f);
    float rj = 1.0f / fmaxf(sqrtf(sj), 1e-12f);
    float riS = ri * SCALE_IN, rjS = rj * SCALE_IN;

    uchar4 ua, ub;
    ua.x = f2fp8(a.x * riS); ua.y = f2fp8(a.y * riS);
    ua.z = f2fp8(a.z * riS); ua.w = f2fp8(a.w * riS);
    ub.x = f2fp8(b.x * rjS); ub.y = f2fp8(b.y * rjS);
    ub.z = f2fp8(b.z * rjS); ub.w = f2fp8(b.w * rjS);

    int ii = i + NPAIR;
    int idxA = (((i  >> 4) * 8 + (l >> 3)) * 512) + ((l >> 1) & 3) * 128
             + (i  & 15) * 8 + (l & 1) * 4;
    int idxB = (((ii >> 4) * 8 + (l >> 3)) * 512) + ((l >> 1) & 3) * 128
             + (ii & 15) * 8 + (l & 1) * 4;
    *(uchar4*)(reps + idxA) = ua;
    *(uchar4*)(reps + idxB) = ub;

    if (l == 0) pdot[i] = dp * ri * rj;       // positives fp32, unscaled
    if (l < 2)  rowsum[2 * i + l] = 0.f;
}

static __device__ __forceinline__ void do_tile(
    int idx, int l, const uint8_t* __restrict__ reps,
    float* __restrict__ rowsum) {
    // anti-diagonal decode over n=128 tile grid: C(d) = d*(257-d)/2
    int d = (int)((257.0f - sqrtf(257.0f * 257.0f - 8.0f * (float)idx)) * 0.5f);
    while (d * (257 - d) / 2 > idx) --d;
    while ((d + 1) * (256 - d) / 2 <= idx) ++d;
    int i0 = idx - d * (257 - d) / 2;
    int brow = i0 * 64;
    int bcol = (i0 + d) * 64;
    int R0A = i0 * 4;
    int R0B = (i0 + d) * 4;

    f32x4 acc[4][4];
    #pragma unroll
    for (int mi = 0; mi < 4; ++mi)
        #pragma unroll
        for (int ni = 0; ni < 4; ++ni)
            acc[mi][ni] = (f32x4){0.f, 0.f, 0.f, 0.f};

    #define LOADF(dstA, dstB, kw)                                              \
        _Pragma("unroll")                                                      \
        for (int q = 0; q < 4; ++q) {                                          \
            dstA[q] = ((const f8frag*)(reps +                                  \
                       (size_t)(((R0A + q) * 8 + (kw)) * 512)))[l];            \
            dstB[q] = ((const f8frag*)(reps +                                  \
                       (size_t)(((R0B + q) * 8 + (kw)) * 512)))[l];            \
        }
    #define MM(a, b)                                                           \
        __builtin_amdgcn_s_setprio(1);                                         \
        _Pragma("unroll")                                                      \
        for (int mi = 0; mi < 4; ++mi)                                         \
            _Pragma("unroll")                                                  \
            for (int ni = 0; ni < 4; ++ni)                                     \
                acc[mi][ni] = __builtin_amdgcn_mfma_f32_16x16x32_fp8_fp8(      \
                    a[mi], b[ni], acc[mi][ni], 0, 0, 0);                       \
        __builtin_amdgcn_s_setprio(0);

    f8frag a0[4], b0[4], a1[4], b1[4];
    LOADF(a0, b0, 0);
    LOADF(a1, b1, 1);
    #pragma unroll
    for (int kw = 0; kw < 8; ++kw) {
        if ((kw & 1) == 0) {
            MM(a0, b0);
            if (kw + 2 < 8) { LOADF(a0, b0, kw + 2); }
        } else {
            MM(a1, b1);
            if (kw + 2 < 8) { LOADF(a1, b1, kw + 2); }
        }
    }
    #undef LOADF
    #undef MM

    // Epilogue. C/D: col = lane&15, row = (lane>>4)*4 + j  [m89/m91]
    // acc already == log2(e)/T * sim -> bare exp2f.
    int frow = l & 15;
    int k16  = l >> 4;
    float csum[4] = {0.f, 0.f, 0.f, 0.f};

    if (d != 0) {                   // off-diagonal: unmasked, rows + cols
        float rv = 0.f;
        #pragma unroll
        for (int mi = 0; mi < 4; ++mi) {
            #pragma unroll
            for (int j = 0; j < 4; ++j) {
                float rp = 0.f;
                #pragma unroll
                for (int ni = 0; ni < 4; ++ni) {
                    float e = exp2f(acc[mi][ni][j]);
                    csum[ni] += e;
                    rp += e;
                }
                rp += __shfl_xor(rp, 1);
                rp += __shfl_xor(rp, 2);
                rp += __shfl_xor(rp, 4);
                rp += __shfl_xor(rp, 8);
                rv = (frow == mi * 4 + j) ? rp : rv;
            }
        }
        #pragma unroll
        for (int ni = 0; ni < 4; ++ni) {
            csum[ni] += __shfl_xor(csum[ni], 16);
            csum[ni] += __shfl_xor(csum[ni], 32);
        }
        float cv = csum[0];
        #pragma unroll
        for (int v = 1; v < 4; ++v) cv = (k16 == v) ? csum[v] : cv;
        atomicAdd(&rowsum[bcol + k16 * 16 + frow], cv);  // 64 disjoint cols
        int grow = brow + (frow >> 2) * 16 + k16 * 4 + (frow & 3);
        atomicAdd(&rowsum[grow], rv);                    // 64 disjoint rows
    } else {                        // diagonal tile: masked, cols only
        int rbase = brow + k16 * 4;
        int cb    = bcol + frow;
        #pragma unroll
        for (int mi = 0; mi < 4; ++mi) {
            #pragma unroll
            for (int j = 0; j < 4; ++j) {
                int grow = rbase + mi * 16 + j;
                #pragma unroll
                for (int ni = 0; ni < 4; ++ni) {
                    float e = exp2f(acc[mi][ni][j]);
                    e = (grow == cb + ni * 16) ? 0.f : e;
                    csum[ni] += e;
                }
            }
        }
        #pragma unroll
        for (int ni = 0; ni < 4; ++ni) {
            csum[ni] += __shfl_xor(csum[ni], 16);
            csum[ni] += __shfl_xor(csum[ni], 32);
        }
        float cv = csum[0];
        #pragma unroll
        for (int v = 1; v < 4; ++v) cv = (k16 == v) ? csum[v] : cv;
        atomicAdd(&rowsum[bcol + k16 * 16 + frow], cv);
    }
}

static __device__ __forceinline__ void do_finalize(
    int t, const float* __restrict__ rowsum, const float* __restrict__ pdot,
    float* __restrict__ out) {
    __shared__ float reds[4], redp[4];
    const float4* rs4 = (const float4*)rowsum;
    const float4* pd4 = (const float4*)pdot;
    float s = 0.f, p = 0.f;
    for (int r = t; r < N2 / 4; r += 256) {
        float4 v = rs4[r];
        s += __logf(v.x) + __logf(v.y) + __logf(v.z) + __logf(v.w);
    }
    for (int r = t; r < NPAIR / 4; r += 256) {
        float4 v = pd4[r];
        p += v.x + v.y + v.z + v.w;
    }
    #pragma unroll
    for (int off = 32; off; off >>= 1) {
        s += __shfl_xor(s, off);
        p += __shfl_xor(p, off);
    }
    if ((t & 63) == 0) { reds[t >> 6] = s; redp[t >> 6] = p; }
    __syncthreads();
    if (t == 0) {
        float S = reds[0] + reds[1] + reds[2] + reds[3];
        float P = redp[0] + redp[1] + redp[2] + redp[3];
        // loss = (sum log D - (2/T)*2*sum(dp)) / 2N ; (2/T)*2 folded: 4*P
        out[0] = (S - 4.0f * P) / (float)N2;
    }
}

// ---------------- fused persistent cooperative kernel ----------------
__global__ __launch_bounds__(256, 2) void fused_kernel(
    const float* __restrict__ emb_i, const float* __restrict__ emb_j,
    uint8_t* __restrict__ reps, float* __restrict__ pdot,
    float* __restrict__ rowsum, float* __restrict__ out) {
    cg::grid_group grid = cg::this_grid();
    int t = threadIdx.x;
    int l = t & 63;
    int gw = blockIdx.x * 4 + (t >> 6);     // 0..2047

    for (int i = gw; i < NPAIR; i += CWAVE)
        do_normalize(i, l, emb_i, emb_j, reps, pdot, rowsum);
    __threadfence();
    grid.sync();

    for (int idx = gw; idx < NTILE; idx += CWAVE)
        do_tile(idx, l, reps, rowsum);
    __threadfence();
    grid.sync();

    if (blockIdx.x == 0) do_finalize(t, rowsum, pdot, out);
}

// ---------------- fallback 3-kernel path (r11 structure) ----------------
__global__ __launch_bounds__(256) void normalize_kernel(
    const float* __restrict__ emb_i, const float* __restrict__ emb_j,
    uint8_t* __restrict__ reps, float* __restrict__ pdot,
    float* __restrict__ rowsum) {
    int i = blockIdx.x * 4 + (threadIdx.x >> 6);
    do_normalize(i, threadIdx.x & 63, emb_i, emb_j, reps, pdot, rowsum);
}

__global__ __launch_bounds__(256, 4) void simexp_kernel(
    const uint8_t* __restrict__ reps, float* __restrict__ rowsum) {
    int idx = blockIdx.x * 4 + (threadIdx.x >> 6);
    do_tile(idx, threadIdx.x & 63, reps, rowsum);
}

__global__ __launch_bounds__(256) void finalize_kernel(
    const float* __restrict__ rowsum, const float* __restrict__ pdot,
    float* __restrict__ out) {
    do_finalize(threadIdx.x, rowsum, pdot, out);
}

extern "C" void kernel_launch(void* const* d_in, const int* in_sizes, int n_in,
                              void* d_out, int out_size, void* d_ws, size_t ws_size,
                              hipStream_t stream) {
    const float* emb_i = (const float*)d_in[0];
    const float* emb_j = (const float*)d_in[1];
    float* out = (float*)d_out;

    char* ws = (char*)d_ws;
    float*    rowsum = (float*)ws;                    // 8192 * 4 B
    float*    pdot   = (float*)(ws + 32768);          // 4096 * 4 B
    uint8_t*  reps   = (uint8_t*)(ws + 65536);        // 8192*256 B (fp8 tiled)

    void* kargs[] = {(void*)&emb_i, (void*)&emb_j, (void*)&reps,
                     (void*)&pdot, (void*)&rowsum, (void*)&out};
    hipError_t e = hipLaunchCooperativeKernel((const void*)fused_kernel,
                                              dim3(CGRID), dim3(256), kargs,
                                              0, stream);
    if (e != hipSuccess) {
        // deterministic fallback: proven 3-kernel path
        normalize_kernel<<<NPAIR / 4, 256, 0, stream>>>(emb_i, emb_j, reps,
                                                        pdot, rowsum);
        simexp_kernel<<<NTILE / 4, 256, 0, stream>>>(reps, rowsum);
        finalize_kernel<<<1, 256, 0, stream>>>(rowsum, pdot, out);
    }
}

// Round 15
// 39.080 us; speedup vs baseline: 6.7709x; 6.7709x over previous
//
#include <hip/hip_runtime.h>
#include <hip/hip_fp8.h>
#include <stdint.h>

#define NPAIR 4096
#define N2    8192      // 2N rows
#define DIM   256
#define NTILE 8256      // 128*129/2 upper-triangle 64x64 tiles
// inputs pre-scaled by sqrt(log2(e)/T): acc == log2(e)/T * sim
#define SCALE_IN 1.6986436f

typedef long  f8frag;   // 8 fp8 elems = 2 VGPR (A/B operand of 16x16x32 fp8)
typedef float f32x4 __attribute__((ext_vector_type(4)));

static __device__ __forceinline__ uint8_t f2fp8(float f) {
    __hip_fp8_e4m3 v(f);                 // OCP e4m3fn, RNE saturating
    return *reinterpret_cast<uint8_t*>(&v);
}

// reps is stored FRAGMENT-TILED fp8: byte index of (row i, dim d) =
//   ((i>>4)*8 + (d>>5))*512 + ((d>>3)&3)*128 + (i&15)*8 + (d&7)
// an MFMA fragment (16 rows x 32 k; lane l -> row l&15, k-slot l>>4) is the
// contiguous 512B block at tile(i>>4, d>>5): lane l reads 8B at base + l*8.

// ---------------- shared phase bodies (verified in r14, absmax 0.0) -------
static __device__ __forceinline__ void do_normalize(
    int i, int l, const float* __restrict__ emb_i,
    const float* __restrict__ emb_j, uint8_t* __restrict__ reps,
    float* __restrict__ pdot, float* __restrict__ rowsum) {
    float4 a = ((const float4*)(emb_i + (size_t)i * DIM))[l];
    float4 b = ((const float4*)(emb_j + (size_t)i * DIM))[l];
    float si = a.x*a.x + a.y*a.y + a.z*a.z + a.w*a.w;
    float sj = b.x*b.x + b.y*b.y + b.z*b.z + b.w*b.w;
    float dp = a.x*b.x + a.y*b.y + a.z*b.z + a.w*b.w;
    #pragma unroll
    for (int off = 32; off; off >>= 1) {
        si += __shfl_xor(si, off);
        sj += __shfl_xor(sj, off);
        dp += __shfl_xor(dp, off);
    }
    float ri = 1.0f / fmaxf(sqrtf(si), 1e-12f);
    float rj = 1.0f / fmaxf(sqrtf(sj), 1e-12f);
    float riS = ri * SCALE_IN, rjS = rj * SCALE_IN;

    uchar4 ua, ub;
    ua.x = f2fp8(a.x * riS); ua.y = f2fp8(a.y * riS);
    ua.z = f2fp8(a.z * riS); ua.w = f2fp8(a.w * riS);
    ub.x = f2fp8(b.x * rjS); ub.y = f2fp8(b.y * rjS);
    ub.z = f2fp8(b.z * rjS); ub.w = f2fp8(b.w * rjS);

    int ii = i + NPAIR;
    int idxA = (((i  >> 4) * 8 + (l >> 3)) * 512) + ((l >> 1) & 3) * 128
             + (i  & 15) * 8 + (l & 1) * 4;
    int idxB = (((ii >> 4) * 8 + (l >> 3)) * 512) + ((l >> 1) & 3) * 128
             + (ii & 15) * 8 + (l & 1) * 4;
    *(uchar4*)(reps + idxA) = ua;
    *(uchar4*)(reps + idxB) = ub;

    if (l == 0) pdot[i] = dp * ri * rj;       // positives fp32, unscaled
    if (l < 2)  rowsum[2 * i + l] = 0.f;
}

static __device__ __forceinline__ void do_tile(
    int idx, int l, const uint8_t* __restrict__ reps,
    float* __restrict__ rowsum) {
    // anti-diagonal decode over n=128 tile grid: C(d) = d*(257-d)/2
    int d = (int)((257.0f - sqrtf(257.0f * 257.0f - 8.0f * (float)idx)) * 0.5f);
    while (d * (257 - d) / 2 > idx) --d;
    while ((d + 1) * (256 - d) / 2 <= idx) ++d;
    int i0 = idx - d * (257 - d) / 2;
    int brow = i0 * 64;
    int bcol = (i0 + d) * 64;
    int R0A = i0 * 4;
    int R0B = (i0 + d) * 4;

    f32x4 acc[4][4];
    #pragma unroll
    for (int mi = 0; mi < 4; ++mi)
        #pragma unroll
        for (int ni = 0; ni < 4; ++ni)
            acc[mi][ni] = (f32x4){0.f, 0.f, 0.f, 0.f};

    #define LOADF(dstA, dstB, kw)                                              \
        _Pragma("unroll")                                                      \
        for (int q = 0; q < 4; ++q) {                                          \
            dstA[q] = ((const f8frag*)(reps +                                  \
                       (size_t)(((R0A + q) * 8 + (kw)) * 512)))[l];            \
            dstB[q] = ((const f8frag*)(reps +                                  \
                       (size_t)(((R0B + q) * 8 + (kw)) * 512)))[l];            \
        }
    #define MM(a, b)                                                           \
        __builtin_amdgcn_s_setprio(1);                                         \
        _Pragma("unroll")                                                      \
        for (int mi = 0; mi < 4; ++mi)                                         \
            _Pragma("unroll")                                                  \
            for (int ni = 0; ni < 4; ++ni)                                     \
                acc[mi][ni] = __builtin_amdgcn_mfma_f32_16x16x32_fp8_fp8(      \
                    a[mi], b[ni], acc[mi][ni], 0, 0, 0);                       \
        __builtin_amdgcn_s_setprio(0);

    f8frag a0[4], b0[4], a1[4], b1[4];
    LOADF(a0, b0, 0);
    LOADF(a1, b1, 1);
    #pragma unroll
    for (int kw = 0; kw < 8; ++kw) {
        if ((kw & 1) == 0) {
            MM(a0, b0);
            if (kw + 2 < 8) { LOADF(a0, b0, kw + 2); }
        } else {
            MM(a1, b1);
            if (kw + 2 < 8) { LOADF(a1, b1, kw + 2); }
        }
    }
    #undef LOADF
    #undef MM

    // Epilogue. C/D: col = lane&15, row = (lane>>4)*4 + j  [m89/m91]
    // acc already == log2(e)/T * sim -> bare exp2f.
    int frow = l & 15;
    int k16  = l >> 4;
    float csum[4] = {0.f, 0.f, 0.f, 0.f};

    if (d != 0) {                   // off-diagonal: unmasked, rows + cols
        float rv = 0.f;
        #pragma unroll
        for (int mi = 0; mi < 4; ++mi) {
            #pragma unroll
            for (int j = 0; j < 4; ++j) {
                float rp = 0.f;
                #pragma unroll
                for (int ni = 0; ni < 4; ++ni) {
                    float e = exp2f(acc[mi][ni][j]);
                    csum[ni] += e;
                    rp += e;
                }
                rp += __shfl_xor(rp, 1);
                rp += __shfl_xor(rp, 2);
                rp += __shfl_xor(rp, 4);
                rp += __shfl_xor(rp, 8);
                rv = (frow == mi * 4 + j) ? rp : rv;
            }
        }
        #pragma unroll
        for (int ni = 0; ni < 4; ++ni) {
            csum[ni] += __shfl_xor(csum[ni], 16);
            csum[ni] += __shfl_xor(csum[ni], 32);
        }
        float cv = csum[0];
        #pragma unroll
        for (int v = 1; v < 4; ++v) cv = (k16 == v) ? csum[v] : cv;
        atomicAdd(&rowsum[bcol + k16 * 16 + frow], cv);  // 64 disjoint cols
        int grow = brow + (frow >> 2) * 16 + k16 * 4 + (frow & 3);
        atomicAdd(&rowsum[grow], rv);                    // 64 disjoint rows
    } else {                        // diagonal tile: masked, cols only
        int rbase = brow + k16 * 4;
        int cb    = bcol + frow;
        #pragma unroll
        for (int mi = 0; mi < 4; ++mi) {
            #pragma unroll
            for (int j = 0; j < 4; ++j) {
                int grow = rbase + mi * 16 + j;
                #pragma unroll
                for (int ni = 0; ni < 4; ++ni) {
                    float e = exp2f(acc[mi][ni][j]);
                    e = (grow == cb + ni * 16) ? 0.f : e;
                    csum[ni] += e;
                }
            }
        }
        #pragma unroll
        for (int ni = 0; ni < 4; ++ni) {
            csum[ni] += __shfl_xor(csum[ni], 16);
            csum[ni] += __shfl_xor(csum[ni], 32);
        }
        float cv = csum[0];
        #pragma unroll
        for (int v = 1; v < 4; ++v) cv = (k16 == v) ? csum[v] : cv;
        atomicAdd(&rowsum[bcol + k16 * 16 + frow], cv);
    }
}

static __device__ __forceinline__ void do_finalize(
    int t, const float* __restrict__ rowsum, const float* __restrict__ pdot,
    float* __restrict__ out) {
    __shared__ float reds[4], redp[4];
    const float4* rs4 = (const float4*)rowsum;
    const float4* pd4 = (const float4*)pdot;
    float s = 0.f, p = 0.f;
    for (int r = t; r < N2 / 4; r += 256) {
        float4 v = rs4[r];
        s += __logf(v.x) + __logf(v.y) + __logf(v.z) + __logf(v.w);
    }
    for (int r = t; r < NPAIR / 4; r += 256) {
        float4 v = pd4[r];
        p += v.x + v.y + v.z + v.w;
    }
    #pragma unroll
    for (int off = 32; off; off >>= 1) {
        s += __shfl_xor(s, off);
        p += __shfl_xor(p, off);
    }
    if ((t & 63) == 0) { reds[t >> 6] = s; redp[t >> 6] = p; }
    __syncthreads();
    if (t == 0) {
        float S = reds[0] + reds[1] + reds[2] + reds[3];
        float P = redp[0] + redp[1] + redp[2] + redp[3];
        // loss = (sum log D - (2/T)*2*sum(dp)) / 2N ; (2/T)*2 folded: 4*P
        out[0] = (S - 4.0f * P) / (float)N2;
    }
}

// ---------------- 3-kernel path ----------------
__global__ __launch_bounds__(256) void normalize_kernel(
    const float* __restrict__ emb_i, const float* __restrict__ emb_j,
    uint8_t* __restrict__ reps, float* __restrict__ pdot,
    float* __restrict__ rowsum) {
    int i = blockIdx.x * 4 + (threadIdx.x >> 6);
    do_normalize(i, threadIdx.x & 63, emb_i, emb_j, reps, pdot, rowsum);
}

__global__ __launch_bounds__(256, 4) void simexp_kernel(
    const uint8_t* __restrict__ reps, float* __restrict__ rowsum) {
    int idx = blockIdx.x * 4 + (threadIdx.x >> 6);
    do_tile(idx, threadIdx.x & 63, reps, rowsum);
}

__global__ __launch_bounds__(256) void finalize_kernel(
    const float* __restrict__ rowsum, const float* __restrict__ pdot,
    float* __restrict__ out) {
    do_finalize(threadIdx.x, rowsum, pdot, out);
}

extern "C" void kernel_launch(void* const* d_in, const int* in_sizes, int n_in,
                              void* d_out, int out_size, void* d_ws, size_t ws_size,
                              hipStream_t stream) {
    const float* emb_i = (const float*)d_in[0];
    const float* emb_j = (const float*)d_in[1];
    float* out = (float*)d_out;

    char* ws = (char*)d_ws;
    float*    rowsum = (float*)ws;                    // 8192 * 4 B
    float*    pdot   = (float*)(ws + 32768);          // 4096 * 4 B
    uint8_t*  reps   = (uint8_t*)(ws + 65536);        // 8192*256 B (fp8 tiled)

    normalize_kernel<<<NPAIR / 4, 256, 0, stream>>>(emb_i, emb_j, reps,
                                                    pdot, rowsum);
    simexp_kernel<<<NTILE / 4, 256, 0, stream>>>(reps, rowsum);
    finalize_kernel<<<1, 256, 0, stream>>>(rowsum, pdot, out);
}